// Round 14
// baseline (107.828 us; speedup 1.0000x reference)
//
#include <hip/hip_runtime.h>

// GCN layer: out = relu( G(feature) @ W^T + b ), G = mean over in-edges (or
// identity for isolated nodes).  N=50000, F=64, E=800000.
//
// GEMM commutes with the aggregation: G(feat)@W^T == G(feat@W^T).
// Round-14: k_scatter was 47us at VALUBusy 0.3% / occupancy 25% -> latency
// bound + 48MB write-amp (scattered 4B stores x 8 incoherent XCD L2s).
// Fixes: 1 edge/thread (4x TLP), nontemporal bucket stores (no L2 alloc ->
// partial-line merge at MC), and GEMM fused with scatter via block-role split
// (independent work overlaps). Pipeline: k_zero -> k_work -> k_gather.

#define F 64
#define CAP 48          // bucket slots per node
#define OVF_MAX 32768   // overflow capacity (never used for this input)

typedef unsigned int uint;
typedef unsigned short ushort;

__device__ __forceinline__ ushort f2bf(float x) {
    uint u = __float_as_uint(x);
    u += 0x7FFFu + ((u >> 16) & 1u);   // round-to-nearest-even
    return (ushort)(u >> 16);
}

// ---------- D1: zero deg + ovf ----------
__global__ __launch_bounds__(256) void k_zero(int* __restrict__ deg, int n4,
                                              int* __restrict__ ovf) {
    int i = blockIdx.x * 256 + threadIdx.x;
    if (i == 0) ovf[0] = 0;
    if (i < n4) ((int4*)deg)[i] = make_int4(0, 0, 0, 0);
}

// ---------- D2: fused GEMM (blocks [0,G)) + scatter (blocks [G, G+S)) ------
__global__ __launch_bounds__(256) void k_work(const float* __restrict__ feature,
                                              const float* __restrict__ W,
                                              ushort* __restrict__ Ybf,
                                              const int* __restrict__ esrc,
                                              const int* __restrict__ edst,
                                              int* __restrict__ deg,
                                              int* __restrict__ bucket,
                                              int* __restrict__ ovf,
                                              int N, int E, int G) {
    __shared__ float sWt[64 * 76];
    __shared__ float shh[32 * 72];
    int tid = threadIdx.x;
    int bid = blockIdx.x;

    if (bid < G) {
        // ---- GEMM role: Ybf[n] = bf16(feature[n] @ W^T) for 32 nodes ----
        for (int i = tid; i < 4096; i += 256) {
            int fo = i >> 6, k = i & 63;
            sWt[k * 76 + fo] = W[i];
        }
        int n0blk = bid * 32;
        for (int i = tid; i < 512; i += 256) {        // 32 rows x 16 float4
            int r = i >> 4, c4 = i & 15;
            int n = n0blk + r;
            float4 v = make_float4(0.f, 0.f, 0.f, 0.f);
            if (n < N) v = ((const float4*)feature)[(long)n * 16 + c4];
            *(float4*)&shh[r * 72 + c4 * 4] = v;
        }
        __syncthreads();
        int npair = tid >> 4, foq = tid & 15;
        int r0 = npair * 2, r1 = r0 + 1;
        float a0=0,a1=0,a2=0,a3=0,b0=0,b1=0,b2=0,b3=0;
#pragma unroll 8
        for (int k = 0; k < 64; ++k) {
            float hA = shh[r0 * 72 + k];
            float hB = shh[r1 * 72 + k];
            float4 wv = *(const float4*)&sWt[k * 76 + foq * 4];
            a0 = fmaf(hA, wv.x, a0); a1 = fmaf(hA, wv.y, a1);
            a2 = fmaf(hA, wv.z, a2); a3 = fmaf(hA, wv.w, a3);
            b0 = fmaf(hB, wv.x, b0); b1 = fmaf(hB, wv.y, b1);
            b2 = fmaf(hB, wv.z, b2); b3 = fmaf(hB, wv.w, b3);
        }
        int nA = n0blk + r0, nB = n0blk + r1;
        if (nA < N) ((ushort4*)Ybf)[(long)nA * 16 + foq] =
            make_ushort4(f2bf(a0), f2bf(a1), f2bf(a2), f2bf(a3));
        if (nB < N) ((ushort4*)Ybf)[(long)nB * 16 + foq] =
            make_ushort4(f2bf(b0), f2bf(b1), f2bf(b2), f2bf(b3));
    } else {
        // ---- scatter role: 1 edge/thread, max TLP ----
        int e = (bid - G) * 256 + tid;
        if (e < E) {
            int d = __builtin_nontemporal_load(edst + e);
            int s = __builtin_nontemporal_load(esrc + e);
            int r = atomicAdd(&deg[d], 1);
            if (r < CAP) {
                __builtin_nontemporal_store(s, bucket + d * CAP + r);
            } else {
                int o = atomicAdd(&ovf[0], 1);
                if (o < OVF_MAX) { ovf[2 + 2*o] = d; ovf[3 + 2*o] = s; }
            }
        }
    }
}

// ---------- D3: gather-mean over bf16 Y + bias + relu ----------
// lane = (g<<3)|c : g = edge slot 0..7, c = ushort8 column 0..7.
__global__ __launch_bounds__(256) void k_gather(const ushort* __restrict__ Ybf,
                                                const int* __restrict__ deg,
                                                const int* __restrict__ bucket,
                                                const int* __restrict__ ovf,
                                                const float* __restrict__ bias,
                                                float* __restrict__ out, int N) {
    int tid = threadIdx.x;
    int w = tid >> 6, lane = tid & 63;
    int g = lane >> 3, c = lane & 7;
    int n = blockIdx.x * 4 + w;
    if (n >= N) return;
    int d = deg[n];
    int m = min(d, CAP);
    int boff = n * CAP;
    const uint4* Y16 = (const uint4*)Ybf;
    float acc[4][8];
#pragma unroll
    for (int ch = 0; ch < 4; ++ch)
#pragma unroll
        for (int j = 0; j < 8; ++j) acc[ch][j] = 0.f;
    int last = m - 1;
    for (int base = 0; base < m; base += 32) {
#pragma unroll
        for (int ch = 0; ch < 4; ++ch) {
            int jdx = base + ch * 8 + g;
            int s = bucket[boff + min(jdx, last)];
            uint4 q = Y16[(long)s * 8 + c];
            if (jdx < m) {
                acc[ch][0] += __uint_as_float(q.x << 16);
                acc[ch][1] += __uint_as_float(q.x & 0xFFFF0000u);
                acc[ch][2] += __uint_as_float(q.y << 16);
                acc[ch][3] += __uint_as_float(q.y & 0xFFFF0000u);
                acc[ch][4] += __uint_as_float(q.z << 16);
                acc[ch][5] += __uint_as_float(q.z & 0xFFFF0000u);
                acc[ch][6] += __uint_as_float(q.w << 16);
                acc[ch][7] += __uint_as_float(q.w & 0xFFFF0000u);
            }
        }
    }
    // overflow tail (empty for this input; correctness for any input).
    if (d > CAP) {
        int no = ovf[0]; if (no > OVF_MAX) no = OVF_MAX;
        if (g == 0) {
            for (int i = 0; i < no; ++i) {
                if (ovf[2 + 2*i] == n) {
                    int s = ovf[3 + 2*i];
                    uint4 q = Y16[(long)s * 8 + c];
                    acc[0][0] += __uint_as_float(q.x << 16);
                    acc[0][1] += __uint_as_float(q.x & 0xFFFF0000u);
                    acc[0][2] += __uint_as_float(q.y << 16);
                    acc[0][3] += __uint_as_float(q.y & 0xFFFF0000u);
                    acc[0][4] += __uint_as_float(q.z << 16);
                    acc[0][5] += __uint_as_float(q.z & 0xFFFF0000u);
                    acc[0][6] += __uint_as_float(q.w << 16);
                    acc[0][7] += __uint_as_float(q.w & 0xFFFF0000u);
                }
            }
        }
    }
#pragma unroll
    for (int j = 0; j < 8; ++j)
        acc[0][j] += (acc[1][j] + acc[2][j]) + acc[3][j];
#pragma unroll
    for (int j = 0; j < 8; ++j) {
        float v = acc[0][j];
        v += __shfl_xor(v, 8);
        v += __shfl_xor(v, 16);
        v += __shfl_xor(v, 32);
        acc[0][j] = v;
    }
    float sel = acc[0][0];
#pragma unroll
    for (int j = 1; j < 8; ++j) sel = (g == j) ? acc[0][j] : sel;
    int fw = c * 8 + g;
    float hv;
    if (d > 0) {
        hv = sel / (float)d;
    } else {
        hv = __uint_as_float(((uint)Ybf[(long)n * F + fw]) << 16);
    }
    out[(long)n * F + fw] = fmaxf(hv + bias[fw], 0.0f);
}

// ---------- fallback tier C: pure atomic (tiny ws) ----------
__global__ __launch_bounds__(256) void gcn_edge_scatter(const float* __restrict__ feature,
                                                        const int* __restrict__ esrc,
                                                        const int* __restrict__ edst,
                                                        float* __restrict__ agg,
                                                        float* __restrict__ cnt, int E) {
    int t = blockIdx.x * blockDim.x + threadIdx.x;
    int e = t >> 6, f = t & 63;
    if (e >= E) return;
    atomicAdd(&agg[(long)edst[e] * F + f], feature[(long)esrc[e] * F + f]);
    if (f == 0) atomicAdd(&cnt[edst[e]], 1.0f);
}
__global__ __launch_bounds__(256) void gcn_node_apply(const float* __restrict__ feature,
                                                      const float* __restrict__ W,
                                                      const float* __restrict__ bias,
                                                      const float* __restrict__ cnt,
                                                      float* __restrict__ inout, int N) {
    __shared__ float sWt[64 * 65];
    __shared__ float sh[4][64];
    int tid = threadIdx.x;
    for (int i = tid; i < 64 * 64; i += 256) {
        int fo = i >> 6, k = i & 63;
        sWt[k * 65 + fo] = W[i];
    }
    int w = tid >> 6, f = tid & 63;
    int n = blockIdx.x * 4 + w;
    float h = 0.0f;
    if (n < N) {
        float c = cnt[n];
        h = (c > 0.0f) ? inout[(long)n * F + f] / c : feature[(long)n * F + f];
    }
    sh[w][f] = h;
    __syncthreads();
    float acc = bias[f];
#pragma unroll
    for (int k = 0; k < 64; ++k) acc = fmaf(sh[w][k], sWt[k * 65 + f], acc);
    if (n < N) inout[(long)n * F + f] = fmaxf(acc, 0.0f);
}

extern "C" void kernel_launch(void* const* d_in, const int* in_sizes, int n_in,
                              void* d_out, int out_size, void* d_ws, size_t ws_size,
                              hipStream_t stream) {
    const float* feature = (const float*)d_in[0];
    const int*   esrc    = (const int*)d_in[1];
    const int*   edst    = (const int*)d_in[2];
    const float* W       = (const float*)d_in[3];
    const float* bias    = (const float*)d_in[4];

    int N = in_sizes[0] / F;   // 50000
    int E = in_sizes[1];       // 800000

    auto align256 = [](size_t x) { return (x + 255) & ~(size_t)255; };
    size_t sz_deg    = align256((size_t)N * sizeof(int));
    size_t sz_ovf    = align256((2 + 2 * (size_t)OVF_MAX) * sizeof(int));
    size_t sz_bucket = align256((size_t)N * CAP * sizeof(int));
    size_t sz_Y      = align256((size_t)N * F * sizeof(ushort));   // bf16
    size_t need = sz_deg + sz_ovf + sz_bucket + sz_Y;

    int n4 = (N + 3) / 4;
    int gZ = (n4 + 255) / 256;
    int G  = (N + 31) / 32;            // GEMM blocks
    int S  = (E + 255) / 256;          // scatter blocks (1 edge/thread)

    if (ws_size >= need) {
        char* ws = (char*)d_ws;
        int*    deg    = (int*)ws;    ws += sz_deg;
        int*    ovf    = (int*)ws;    ws += sz_ovf;
        int*    bucket = (int*)ws;    ws += sz_bucket;
        ushort* Ybf    = (ushort*)ws;
        float*  out    = (float*)d_out;

        k_zero<<<gZ, 256, 0, stream>>>(deg, n4, ovf);
        k_work<<<G + S, 256, 0, stream>>>(feature, W, Ybf, esrc, edst,
                                          deg, bucket, ovf, N, E, G);
        k_gather<<<(N + 3) / 4, 256, 0, stream>>>(Ybf, deg, bucket, ovf, bias, out, N);
    } else {
        float* agg = (float*)d_out;
        float* cnt = (float*)d_ws;
        hipMemsetAsync(agg, 0, (size_t)N * F * sizeof(float), stream);
        hipMemsetAsync(cnt, 0, (size_t)N * sizeof(float), stream);
        long total = (long)E * F;
        gcn_edge_scatter<<<(int)((total + 255) / 256), 256, 0, stream>>>(
            feature, esrc, edst, agg, cnt, E);
        gcn_node_apply<<<(N + 3) / 4, 256, 0, stream>>>(feature, W, bias, cnt, agg, N);
    }
}

// Round 15
// 88.488 us; speedup vs baseline: 1.2186x; 1.2186x over previous
//
#include <hip/hip_runtime.h>

// GCN layer: out = relu( G(feature) @ W^T + b ), G = mean over in-edges (or
// identity for isolated nodes).  N=50000, F=64, E=800000.
//
// GEMM commutes with the aggregation: G(feat)@W^T == G(feat@W^T).
// Round-15: XCD-partitioned scatter. Round-13's 47us scatter was write-amp
// bound: 800K scattered 4B stores via 8 non-coherent XCD L2s -> no merging,
// 48MB HBM writes. Now blocks on XCD x (bid&7==x, round-robin dispatch)
// process only edges with (dst&7)==x: all stores to a node's 192B bucket
// region come from one XCD -> merge in its L2 (1.2MB share < 4MB). Each
// sub-grid re-scans the edge list (8x reads, L3-served). Correct regardless
// of the actual bid->XCD mapping (only merge-perf depends on it).
// (R14 lessons: NT stores kill merging entirely, 55MB writes; 1 edge/thread
// kills MLP; GEMM-fusion taxes scatter with 28KB LDS. All reverted.)
// Pipeline: k_gemm(+zero deg/ovf) -> k_scatter -> k_gather.

#define F 64
#define CAP 48          // bucket slots per node: 192B = 3 full 64B lines
#define OVF_MAX 32768   // overflow capacity (never used for this input)

typedef unsigned int uint;
typedef unsigned short ushort;

__device__ __forceinline__ ushort f2bf(float x) {
    uint u = __float_as_uint(x);
    u += 0x7FFFu + ((u >> 16) & 1u);   // round-to-nearest-even
    return (ushort)(u >> 16);
}

// ---------- D1: Ybf = bf16( feature @ W^T ), plus deg/ovf zeroing ----------
__global__ __launch_bounds__(256) void k_gemm(const float* __restrict__ feature,
                                              const float* __restrict__ W,
                                              ushort* __restrict__ Ybf, int N,
                                              int* __restrict__ deg, int n4,
                                              int* __restrict__ ovf) {
    {
        int gt = blockIdx.x * 256 + threadIdx.x;
        if (gt == 0) ovf[0] = 0;
        for (int i = gt; i < n4; i += gridDim.x * 256)
            ((int4*)deg)[i] = make_int4(0, 0, 0, 0);
    }
    __shared__ float sWt[64 * 76];
    __shared__ float shh[32 * 72];
    int tid = threadIdx.x;
    for (int i = tid; i < 4096; i += 256) {
        int fo = i >> 6, k = i & 63;
        sWt[k * 76 + fo] = W[i];
    }
    int n0blk = blockIdx.x * 32;
    for (int i = tid; i < 512; i += 256) {        // 32 rows x 16 float4
        int r = i >> 4, c4 = i & 15;
        int n = n0blk + r;
        float4 v = make_float4(0.f, 0.f, 0.f, 0.f);
        if (n < N) v = ((const float4*)feature)[(long)n * 16 + c4];
        *(float4*)&shh[r * 72 + c4 * 4] = v;
    }
    __syncthreads();
    int npair = tid >> 4, foq = tid & 15;
    int r0 = npair * 2, r1 = r0 + 1;
    float a0=0,a1=0,a2=0,a3=0,b0=0,b1=0,b2=0,b3=0;
#pragma unroll 8
    for (int k = 0; k < 64; ++k) {
        float hA = shh[r0 * 72 + k];
        float hB = shh[r1 * 72 + k];
        float4 wv = *(const float4*)&sWt[k * 76 + foq * 4];
        a0 = fmaf(hA, wv.x, a0); a1 = fmaf(hA, wv.y, a1);
        a2 = fmaf(hA, wv.z, a2); a3 = fmaf(hA, wv.w, a3);
        b0 = fmaf(hB, wv.x, b0); b1 = fmaf(hB, wv.y, b1);
        b2 = fmaf(hB, wv.z, b2); b3 = fmaf(hB, wv.w, b3);
    }
    int nA = n0blk + r0, nB = n0blk + r1;
    if (nA < N) ((ushort4*)Ybf)[(long)nA * 16 + foq] =
        make_ushort4(f2bf(a0), f2bf(a1), f2bf(a2), f2bf(a3));
    if (nB < N) ((ushort4*)Ybf)[(long)nB * 16 + foq] =
        make_ushort4(f2bf(b0), f2bf(b1), f2bf(b2), f2bf(b3));
}

// ---------- D2: XCD-partitioned histogram + direct bucket scatter ----------
// Blocks with bid&7 == x handle only edges whose (dst&7) == x. Grid-stride
// per sub-grid; 4 edges/thread/iter for MLP.
__global__ __launch_bounds__(256) void k_scatter(const int* __restrict__ esrc,
                                                 const int* __restrict__ edst,
                                                 int* __restrict__ deg,
                                                 int* __restrict__ bucket,
                                                 int* __restrict__ ovf, int E) {
    int myx  = blockIdx.x & 7;
    int sub  = blockIdx.x >> 3;
    int nsub = gridDim.x >> 3;          // blocks per sub-grid
    int tid  = threadIdx.x;
    int nq   = (E + 3) >> 2;

    for (int q = sub * 256 + tid; q < nq; q += nsub * 256) {
        int base = q * 4;
        if (base + 3 < E) {
            int4 d4 = *(const int4*)(edst + base);
            int4 s4 = *(const int4*)(esrc + base);
            if ((d4.x & 7) == myx) {
                int r = atomicAdd(&deg[d4.x], 1);
                if (r < CAP) bucket[d4.x * CAP + r] = s4.x;
                else { int o = atomicAdd(&ovf[0], 1); if (o < OVF_MAX) { ovf[2 + 2*o] = d4.x; ovf[3 + 2*o] = s4.x; } }
            }
            if ((d4.y & 7) == myx) {
                int r = atomicAdd(&deg[d4.y], 1);
                if (r < CAP) bucket[d4.y * CAP + r] = s4.y;
                else { int o = atomicAdd(&ovf[0], 1); if (o < OVF_MAX) { ovf[2 + 2*o] = d4.y; ovf[3 + 2*o] = s4.y; } }
            }
            if ((d4.z & 7) == myx) {
                int r = atomicAdd(&deg[d4.z], 1);
                if (r < CAP) bucket[d4.z * CAP + r] = s4.z;
                else { int o = atomicAdd(&ovf[0], 1); if (o < OVF_MAX) { ovf[2 + 2*o] = d4.z; ovf[3 + 2*o] = s4.z; } }
            }
            if ((d4.w & 7) == myx) {
                int r = atomicAdd(&deg[d4.w], 1);
                if (r < CAP) bucket[d4.w * CAP + r] = s4.w;
                else { int o = atomicAdd(&ovf[0], 1); if (o < OVF_MAX) { ovf[2 + 2*o] = d4.w; ovf[3 + 2*o] = s4.w; } }
            }
        } else {
            for (int e = base; e < E; ++e) {
                int d = edst[e];
                if ((d & 7) != myx) continue;
                int s = esrc[e];
                int r = atomicAdd(&deg[d], 1);
                if (r < CAP) bucket[d * CAP + r] = s;
                else { int o = atomicAdd(&ovf[0], 1); if (o < OVF_MAX) { ovf[2 + 2*o] = d; ovf[3 + 2*o] = s; } }
            }
        }
    }
}

// ---------- D3: gather-mean over bf16 Y + bias + relu ----------
// lane = (g<<3)|c : g = edge slot 0..7, c = ushort8 column 0..7.
__global__ __launch_bounds__(256) void k_gather(const ushort* __restrict__ Ybf,
                                                const int* __restrict__ deg,
                                                const int* __restrict__ bucket,
                                                const int* __restrict__ ovf,
                                                const float* __restrict__ bias,
                                                float* __restrict__ out, int N) {
    int tid = threadIdx.x;
    int w = tid >> 6, lane = tid & 63;
    int g = lane >> 3, c = lane & 7;
    int n = blockIdx.x * 4 + w;
    if (n >= N) return;
    int d = deg[n];
    int m = min(d, CAP);
    int boff = n * CAP;
    const uint4* Y16 = (const uint4*)Ybf;
    float acc[4][8];
#pragma unroll
    for (int ch = 0; ch < 4; ++ch)
#pragma unroll
        for (int j = 0; j < 8; ++j) acc[ch][j] = 0.f;
    int last = m - 1;
    for (int base = 0; base < m; base += 32) {
#pragma unroll
        for (int ch = 0; ch < 4; ++ch) {
            int jdx = base + ch * 8 + g;
            int s = bucket[boff + min(jdx, last)];
            uint4 q = Y16[(long)s * 8 + c];
            if (jdx < m) {
                acc[ch][0] += __uint_as_float(q.x << 16);
                acc[ch][1] += __uint_as_float(q.x & 0xFFFF0000u);
                acc[ch][2] += __uint_as_float(q.y << 16);
                acc[ch][3] += __uint_as_float(q.y & 0xFFFF0000u);
                acc[ch][4] += __uint_as_float(q.z << 16);
                acc[ch][5] += __uint_as_float(q.z & 0xFFFF0000u);
                acc[ch][6] += __uint_as_float(q.w << 16);
                acc[ch][7] += __uint_as_float(q.w & 0xFFFF0000u);
            }
        }
    }
    // overflow tail (empty for this input; correctness for any input).
    if (d > CAP) {
        int no = ovf[0]; if (no > OVF_MAX) no = OVF_MAX;
        if (g == 0) {
            for (int i = 0; i < no; ++i) {
                if (ovf[2 + 2*i] == n) {
                    int s = ovf[3 + 2*i];
                    uint4 q = Y16[(long)s * 8 + c];
                    acc[0][0] += __uint_as_float(q.x << 16);
                    acc[0][1] += __uint_as_float(q.x & 0xFFFF0000u);
                    acc[0][2] += __uint_as_float(q.y << 16);
                    acc[0][3] += __uint_as_float(q.y & 0xFFFF0000u);
                    acc[0][4] += __uint_as_float(q.z << 16);
                    acc[0][5] += __uint_as_float(q.z & 0xFFFF0000u);
                    acc[0][6] += __uint_as_float(q.w << 16);
                    acc[0][7] += __uint_as_float(q.w & 0xFFFF0000u);
                }
            }
        }
    }
#pragma unroll
    for (int j = 0; j < 8; ++j)
        acc[0][j] += (acc[1][j] + acc[2][j]) + acc[3][j];
#pragma unroll
    for (int j = 0; j < 8; ++j) {
        float v = acc[0][j];
        v += __shfl_xor(v, 8);
        v += __shfl_xor(v, 16);
        v += __shfl_xor(v, 32);
        acc[0][j] = v;
    }
    float sel = acc[0][0];
#pragma unroll
    for (int j = 1; j < 8; ++j) sel = (g == j) ? acc[0][j] : sel;
    int fw = c * 8 + g;
    float hv;
    if (d > 0) {
        hv = sel / (float)d;
    } else {
        hv = __uint_as_float(((uint)Ybf[(long)n * F + fw]) << 16);
    }
    out[(long)n * F + fw] = fmaxf(hv + bias[fw], 0.0f);
}

// ---------- fallback tier C: pure atomic (tiny ws) ----------
__global__ __launch_bounds__(256) void gcn_edge_scatter(const float* __restrict__ feature,
                                                        const int* __restrict__ esrc,
                                                        const int* __restrict__ edst,
                                                        float* __restrict__ agg,
                                                        float* __restrict__ cnt, int E) {
    int t = blockIdx.x * blockDim.x + threadIdx.x;
    int e = t >> 6, f = t & 63;
    if (e >= E) return;
    atomicAdd(&agg[(long)edst[e] * F + f], feature[(long)esrc[e] * F + f]);
    if (f == 0) atomicAdd(&cnt[edst[e]], 1.0f);
}
__global__ __launch_bounds__(256) void gcn_node_apply(const float* __restrict__ feature,
                                                      const float* __restrict__ W,
                                                      const float* __restrict__ bias,
                                                      const float* __restrict__ cnt,
                                                      float* __restrict__ inout, int N) {
    __shared__ float sWt[64 * 65];
    __shared__ float sh[4][64];
    int tid = threadIdx.x;
    for (int i = tid; i < 64 * 64; i += 256) {
        int fo = i >> 6, k = i & 63;
        sWt[k * 65 + fo] = W[i];
    }
    int w = tid >> 6, f = tid & 63;
    int n = blockIdx.x * 4 + w;
    float h = 0.0f;
    if (n < N) {
        float c = cnt[n];
        h = (c > 0.0f) ? inout[(long)n * F + f] / c : feature[(long)n * F + f];
    }
    sh[w][f] = h;
    __syncthreads();
    float acc = bias[f];
#pragma unroll
    for (int k = 0; k < 64; ++k) acc = fmaf(sh[w][k], sWt[k * 65 + f], acc);
    if (n < N) inout[(long)n * F + f] = fmaxf(acc, 0.0f);
}

extern "C" void kernel_launch(void* const* d_in, const int* in_sizes, int n_in,
                              void* d_out, int out_size, void* d_ws, size_t ws_size,
                              hipStream_t stream) {
    const float* feature = (const float*)d_in[0];
    const int*   esrc    = (const int*)d_in[1];
    const int*   edst    = (const int*)d_in[2];
    const float* W       = (const float*)d_in[3];
    const float* bias    = (const float*)d_in[4];

    int N = in_sizes[0] / F;   // 50000
    int E = in_sizes[1];       // 800000

    auto align256 = [](size_t x) { return (x + 255) & ~(size_t)255; };
    size_t sz_deg    = align256((size_t)N * sizeof(int));
    size_t sz_ovf    = align256((2 + 2 * (size_t)OVF_MAX) * sizeof(int));
    size_t sz_bucket = align256((size_t)N * CAP * sizeof(int));
    size_t sz_Y      = align256((size_t)N * F * sizeof(ushort));   // bf16
    size_t need = sz_deg + sz_ovf + sz_bucket + sz_Y;

    int n4 = (N + 3) / 4;

    if (ws_size >= need) {
        char* ws = (char*)d_ws;
        int*    deg    = (int*)ws;    ws += sz_deg;
        int*    ovf    = (int*)ws;    ws += sz_ovf;
        int*    bucket = (int*)ws;    ws += sz_bucket;
        ushort* Ybf    = (ushort*)ws;
        float*  out    = (float*)d_out;

        k_gemm<<<(N + 31) / 32, 256, 0, stream>>>(feature, W, Ybf, N, deg, n4, ovf);
        // 1024 blocks = 8 sub-grids x 128 blocks; each sub-grid scans all edges
        k_scatter<<<1024, 256, 0, stream>>>(esrc, edst, deg, bucket, ovf, E);
        k_gather<<<(N + 3) / 4, 256, 0, stream>>>(Ybf, deg, bucket, ovf, bias, out, N);
    } else {
        float* agg = (float*)d_out;
        float* cnt = (float*)d_ws;
        hipMemsetAsync(agg, 0, (size_t)N * F * sizeof(float), stream);
        hipMemsetAsync(cnt, 0, (size_t)N * sizeof(float), stream);
        long total = (long)E * F;
        gcn_edge_scatter<<<(int)((total + 255) / 256), 256, 0, stream>>>(
            feature, esrc, edst, agg, cnt, E);
        gcn_node_apply<<<(N + 3) / 4, 256, 0, stream>>>(feature, W, bias, cnt, agg, N);
    }
}

// Round 16
// 74.980 us; speedup vs baseline: 1.4381x; 1.1802x over previous
//
#include <hip/hip_runtime.h>

// GCN layer: out = relu( G(feature) @ W^T + b ), G = mean over in-edges (or
// identity for isolated nodes).  N=50000, F=64, E=800000.
//
// GEMM commutes with the aggregation: G(feat)@W^T == G(feat@W^T).
// Round-16: two-pass shard sort replaces the atomic scatter. R13/R15 evidence:
// 800K device-scope atomics + 800K scattered 4B stores are fabric-line-op
// bound (~44us) and XCD partitioning can't help (atomics bypass L2).
//   pass1 k_shard: LDS-histogram by shard (dst>>8), LDS scan, shard-sorted
//     staging, bulk-append per (block,shard) = 77K coarse atomics + ~10-edge
//     contiguous runs (merged writes).
//   pass2 k_bin: 1 block/shard, LDS-atomic binning (cheap), coalesced
//     deg+bucket writeback.
// Overflow lists (A: shard cap, B: deg>CAP) keep any-input correctness.
// Pipeline: k_gemm(+zero) -> k_shard -> k_bin -> k_gather.

#define F 64
#define CAP 48          // bucket slots per node
#define SHW 256         // nodes per shard
#define OVF_MAX 32768

typedef unsigned int uint;
typedef unsigned short ushort;

__device__ __forceinline__ ushort f2bf(float x) {
    uint u = __float_as_uint(x);
    u += 0x7FFFu + ((u >> 16) & 1u);   // round-to-nearest-even
    return (ushort)(u >> 16);
}

// ---------- D1: Ybf = bf16( feature @ W^T ), plus zeroing ----------
__global__ __launch_bounds__(256) void k_gemm(const float* __restrict__ feature,
                                              const float* __restrict__ W,
                                              ushort* __restrict__ Ybf, int N,
                                              int* __restrict__ deg, int n4,
                                              int* __restrict__ cursor,
                                              int* __restrict__ ovfA,
                                              int* __restrict__ ovfB) {
    {
        int gt = blockIdx.x * 256 + threadIdx.x;
        if (gt < 256) cursor[gt] = 0;
        if (gt == 0) { ovfA[0] = 0; ovfB[0] = 0; }
        for (int i = gt; i < n4; i += gridDim.x * 256)
            ((int4*)deg)[i] = make_int4(0, 0, 0, 0);
    }
    __shared__ float sWt[64 * 76];
    __shared__ float shh[32 * 72];
    int tid = threadIdx.x;
    for (int i = tid; i < 4096; i += 256) {
        int fo = i >> 6, k = i & 63;
        sWt[k * 76 + fo] = W[i];
    }
    int n0blk = blockIdx.x * 32;
    for (int i = tid; i < 512; i += 256) {        // 32 rows x 16 float4
        int r = i >> 4, c4 = i & 15;
        int n = n0blk + r;
        float4 v = make_float4(0.f, 0.f, 0.f, 0.f);
        if (n < N) v = ((const float4*)feature)[(long)n * 16 + c4];
        *(float4*)&shh[r * 72 + c4 * 4] = v;
    }
    __syncthreads();
    int npair = tid >> 4, foq = tid & 15;
    int r0 = npair * 2, r1 = r0 + 1;
    float a0=0,a1=0,a2=0,a3=0,b0=0,b1=0,b2=0,b3=0;
#pragma unroll 8
    for (int k = 0; k < 64; ++k) {
        float hA = shh[r0 * 72 + k];
        float hB = shh[r1 * 72 + k];
        float4 wv = *(const float4*)&sWt[k * 76 + foq * 4];
        a0 = fmaf(hA, wv.x, a0); a1 = fmaf(hA, wv.y, a1);
        a2 = fmaf(hA, wv.z, a2); a3 = fmaf(hA, wv.w, a3);
        b0 = fmaf(hB, wv.x, b0); b1 = fmaf(hB, wv.y, b1);
        b2 = fmaf(hB, wv.z, b2); b3 = fmaf(hB, wv.w, b3);
    }
    int nA = n0blk + r0, nB = n0blk + r1;
    if (nA < N) ((ushort4*)Ybf)[(long)nA * 16 + foq] =
        make_ushort4(f2bf(a0), f2bf(a1), f2bf(a2), f2bf(a3));
    if (nB < N) ((ushort4*)Ybf)[(long)nB * 16 + foq] =
        make_ushort4(f2bf(b0), f2bf(b1), f2bf(b2), f2bf(b3));
}

// ---------- D2 pass 1: shard-sort edges (2048 edges/block) ----------
__global__ __launch_bounds__(256) void k_shard(const int* __restrict__ esrc,
                                               const int* __restrict__ edst,
                                               int* __restrict__ cursor,
                                               int2* __restrict__ shardBuf,
                                               int* __restrict__ ovfA,
                                               int E, int NSH, int CAPS) {
    __shared__ int cnt[256], pfx[256], base_g[256], off[256];
    __shared__ int sc[256];
    __shared__ int2 stage[2048];
    __shared__ ushort stsh[2048];

    int tid = threadIdx.x;
    int eb  = blockIdx.x * 2048;
    int d[8], s[8];
    int i0 = eb + tid * 8;
    bool full = (i0 + 7 < E);
    if (full) {
        int4 a = *(const int4*)(edst + i0);
        int4 b = *(const int4*)(edst + i0 + 4);
        d[0]=a.x; d[1]=a.y; d[2]=a.z; d[3]=a.w;
        d[4]=b.x; d[5]=b.y; d[6]=b.z; d[7]=b.w;
        int4 c = *(const int4*)(esrc + i0);
        int4 e4 = *(const int4*)(esrc + i0 + 4);
        s[0]=c.x; s[1]=c.y; s[2]=c.z; s[3]=c.w;
        s[4]=e4.x; s[5]=e4.y; s[6]=e4.z; s[7]=e4.w;
    } else {
#pragma unroll
        for (int k = 0; k < 8; ++k) {
            int e = i0 + k;
            d[k] = (e < E) ? edst[e] : -1;
            s[k] = (e < E) ? esrc[e] : 0;
        }
    }
    for (int i = tid; i < 256; i += 256) cnt[i] = 0;
    __syncthreads();
#pragma unroll
    for (int k = 0; k < 8; ++k)
        if (d[k] >= 0) atomicAdd(&cnt[d[k] >> 8], 1);
    __syncthreads();
    // exclusive scan over 256 shard counts (Hillis-Steele)
    int own = cnt[tid];
    sc[tid] = own;
    __syncthreads();
    for (int dd = 1; dd < 256; dd <<= 1) {
        int t = (tid >= dd) ? sc[tid - dd] : 0;
        __syncthreads();
        sc[tid] += t;
        __syncthreads();
    }
    pfx[tid] = sc[tid] - own;
    off[tid] = sc[tid] - own;
    if (tid < NSH && own > 0) base_g[tid] = atomicAdd(&cursor[tid], own);
    __syncthreads();
#pragma unroll
    for (int k = 0; k < 8; ++k) {
        if (d[k] >= 0) {
            int sh = d[k] >> 8;
            int sl = atomicAdd(&off[sh], 1);
            stage[sl] = make_int2(d[k], s[k]);
            stsh[sl] = (ushort)sh;
        }
    }
    __syncthreads();
    int total = pfx[255] + cnt[255];
    for (int i = tid; i < total; i += 256) {
        int sh = stsh[i];
        int pos = base_g[sh] + (i - pfx[sh]);
        int2 p = stage[i];
        if (pos < CAPS) {
            shardBuf[(long)sh * CAPS + pos] = p;
        } else {
            int o = atomicAdd(&ovfA[0], 1);
            if (o < OVF_MAX) { ovfA[2 + 2*o] = p.x; ovfA[3 + 2*o] = p.y; }
        }
    }
}

// ---------- D2 pass 2: per-shard LDS binning + coalesced writeback ----------
__global__ __launch_bounds__(256) void k_bin(const int2* __restrict__ shardBuf,
                                             const int* __restrict__ cursor,
                                             const int* __restrict__ ovfA,
                                             int* __restrict__ deg,
                                             int* __restrict__ bucket,
                                             int* __restrict__ ovfB,
                                             int N, int CAPS) {
    __shared__ int dl[SHW];
    __shared__ int bl[SHW * CAP];   // 48KB
    int tid = threadIdx.x;
    int sh  = blockIdx.x;
    for (int i = tid; i < SHW; i += 256) dl[i] = 0;
    __syncthreads();
    int cnt_s = cursor[sh]; if (cnt_s > CAPS) cnt_s = CAPS;
    for (int i = tid; i < cnt_s; i += 256) {
        int2 p = shardBuf[(long)sh * CAPS + i];
        int lid = p.x - sh * SHW;
        int r = atomicAdd(&dl[lid], 1);
        if (r < CAP) bl[lid * CAP + r] = p.y;
        else { int o = atomicAdd(&ovfB[0], 1);
               if (o < OVF_MAX) { ovfB[2 + 2*o] = p.x; ovfB[3 + 2*o] = p.y; } }
    }
    int na = ovfA[0]; if (na > OVF_MAX) na = OVF_MAX;
    for (int i = tid; i < na; i += 256) {
        int dv = ovfA[2 + 2*i];
        if ((dv >> 8) == sh) {
            int lid = dv - sh * SHW;
            int r = atomicAdd(&dl[lid], 1);
            if (r < CAP) bl[lid * CAP + r] = ovfA[3 + 2*i];
            else { int o = atomicAdd(&ovfB[0], 1);
                   if (o < OVF_MAX) { ovfB[2 + 2*o] = dv; ovfB[3 + 2*o] = ovfA[3 + 2*i]; } }
        }
    }
    __syncthreads();
    int n0 = sh * SHW;
    for (int i = tid; i < SHW; i += 256) {
        int n = n0 + i;
        if (n < N) deg[n] = dl[i];
    }
    for (int j = tid; j < SHW * CAP; j += 256) {
        int row = j / CAP;
        if (n0 + row < N) bucket[(long)n0 * CAP + j] = bl[j];
    }
}

// ---------- D3: gather-mean over bf16 Y + bias + relu ----------
__global__ __launch_bounds__(256) void k_gather(const ushort* __restrict__ Ybf,
                                                const int* __restrict__ deg,
                                                const int* __restrict__ bucket,
                                                const int* __restrict__ ovf,
                                                const float* __restrict__ bias,
                                                float* __restrict__ out, int N) {
    int tid = threadIdx.x;
    int w = tid >> 6, lane = tid & 63;
    int g = lane >> 3, c = lane & 7;
    int n = blockIdx.x * 4 + w;
    if (n >= N) return;
    int d = deg[n];
    int m = min(d, CAP);
    int boff = n * CAP;
    const uint4* Y16 = (const uint4*)Ybf;
    float acc[4][8];
#pragma unroll
    for (int ch = 0; ch < 4; ++ch)
#pragma unroll
        for (int j = 0; j < 8; ++j) acc[ch][j] = 0.f;
    int last = m - 1;
    for (int base = 0; base < m; base += 32) {
#pragma unroll
        for (int ch = 0; ch < 4; ++ch) {
            int jdx = base + ch * 8 + g;
            int s = bucket[boff + min(jdx, last)];
            uint4 q = Y16[(long)s * 8 + c];
            if (jdx < m) {
                acc[ch][0] += __uint_as_float(q.x << 16);
                acc[ch][1] += __uint_as_float(q.x & 0xFFFF0000u);
                acc[ch][2] += __uint_as_float(q.y << 16);
                acc[ch][3] += __uint_as_float(q.y & 0xFFFF0000u);
                acc[ch][4] += __uint_as_float(q.z << 16);
                acc[ch][5] += __uint_as_float(q.z & 0xFFFF0000u);
                acc[ch][6] += __uint_as_float(q.w << 16);
                acc[ch][7] += __uint_as_float(q.w & 0xFFFF0000u);
            }
        }
    }
    if (d > CAP) {   // overflow tail (empty for this input)
        int no = ovf[0]; if (no > OVF_MAX) no = OVF_MAX;
        if (g == 0) {
            for (int i = 0; i < no; ++i) {
                if (ovf[2 + 2*i] == n) {
                    int s = ovf[3 + 2*i];
                    uint4 q = Y16[(long)s * 8 + c];
                    acc[0][0] += __uint_as_float(q.x << 16);
                    acc[0][1] += __uint_as_float(q.x & 0xFFFF0000u);
                    acc[0][2] += __uint_as_float(q.y << 16);
                    acc[0][3] += __uint_as_float(q.y & 0xFFFF0000u);
                    acc[0][4] += __uint_as_float(q.z << 16);
                    acc[0][5] += __uint_as_float(q.z & 0xFFFF0000u);
                    acc[0][6] += __uint_as_float(q.w << 16);
                    acc[0][7] += __uint_as_float(q.w & 0xFFFF0000u);
                }
            }
        }
    }
#pragma unroll
    for (int j = 0; j < 8; ++j)
        acc[0][j] += (acc[1][j] + acc[2][j]) + acc[3][j];
#pragma unroll
    for (int j = 0; j < 8; ++j) {
        float v = acc[0][j];
        v += __shfl_xor(v, 8);
        v += __shfl_xor(v, 16);
        v += __shfl_xor(v, 32);
        acc[0][j] = v;
    }
    float sel = acc[0][0];
#pragma unroll
    for (int j = 1; j < 8; ++j) sel = (g == j) ? acc[0][j] : sel;
    int fw = c * 8 + g;
    float hv;
    if (d > 0) {
        hv = sel / (float)d;
    } else {
        hv = __uint_as_float(((uint)Ybf[(long)n * F + fw]) << 16);
    }
    out[(long)n * F + fw] = fmaxf(hv + bias[fw], 0.0f);
}

// ---------- mid-tier: R13 direct atomic scatter (if ws too small for shard) --
__global__ __launch_bounds__(256) void k_scatter13(const int* __restrict__ esrc,
                                                   const int* __restrict__ edst,
                                                   int* __restrict__ deg,
                                                   int* __restrict__ bucket,
                                                   int* __restrict__ ovfB, int E) {
    int base = (blockIdx.x * 256 + threadIdx.x) * 4;
    if (base + 3 < E) {
        int4 d4 = *(const int4*)(edst + base);
        int4 s4 = *(const int4*)(esrc + base);
        int r0 = atomicAdd(&deg[d4.x], 1);
        int r1 = atomicAdd(&deg[d4.y], 1);
        int r2 = atomicAdd(&deg[d4.z], 1);
        int r3 = atomicAdd(&deg[d4.w], 1);
        if (r0 < CAP) bucket[d4.x * CAP + r0] = s4.x;
        else { int o = atomicAdd(&ovfB[0], 1); if (o < OVF_MAX) { ovfB[2 + 2*o] = d4.x; ovfB[3 + 2*o] = s4.x; } }
        if (r1 < CAP) bucket[d4.y * CAP + r1] = s4.y;
        else { int o = atomicAdd(&ovfB[0], 1); if (o < OVF_MAX) { ovfB[2 + 2*o] = d4.y; ovfB[3 + 2*o] = s4.y; } }
        if (r2 < CAP) bucket[d4.z * CAP + r2] = s4.z;
        else { int o = atomicAdd(&ovfB[0], 1); if (o < OVF_MAX) { ovfB[2 + 2*o] = d4.z; ovfB[3 + 2*o] = s4.z; } }
        if (r3 < CAP) bucket[d4.w * CAP + r3] = s4.w;
        else { int o = atomicAdd(&ovfB[0], 1); if (o < OVF_MAX) { ovfB[2 + 2*o] = d4.w; ovfB[3 + 2*o] = s4.w; } }
    } else {
        for (int e = base; e < E; ++e) {
            int d = edst[e], s = esrc[e];
            int r = atomicAdd(&deg[d], 1);
            if (r < CAP) bucket[d * CAP + r] = s;
            else { int o = atomicAdd(&ovfB[0], 1); if (o < OVF_MAX) { ovfB[2 + 2*o] = d; ovfB[3 + 2*o] = s; } }
        }
    }
}

// ---------- fallback tier C: pure atomic (tiny ws) ----------
__global__ __launch_bounds__(256) void gcn_edge_scatter(const float* __restrict__ feature,
                                                        const int* __restrict__ esrc,
                                                        const int* __restrict__ edst,
                                                        float* __restrict__ agg,
                                                        float* __restrict__ cnt, int E) {
    int t = blockIdx.x * blockDim.x + threadIdx.x;
    int e = t >> 6, f = t & 63;
    if (e >= E) return;
    atomicAdd(&agg[(long)edst[e] * F + f], feature[(long)esrc[e] * F + f]);
    if (f == 0) atomicAdd(&cnt[edst[e]], 1.0f);
}
__global__ __launch_bounds__(256) void gcn_node_apply(const float* __restrict__ feature,
                                                      const float* __restrict__ W,
                                                      const float* __restrict__ bias,
                                                      const float* __restrict__ cnt,
                                                      float* __restrict__ inout, int N) {
    __shared__ float sWt[64 * 65];
    __shared__ float sh[4][64];
    int tid = threadIdx.x;
    for (int i = tid; i < 64 * 64; i += 256) {
        int fo = i >> 6, k = i & 63;
        sWt[k * 65 + fo] = W[i];
    }
    int w = tid >> 6, f = tid & 63;
    int n = blockIdx.x * 4 + w;
    float h = 0.0f;
    if (n < N) {
        float c = cnt[n];
        h = (c > 0.0f) ? inout[(long)n * F + f] / c : feature[(long)n * F + f];
    }
    sh[w][f] = h;
    __syncthreads();
    float acc = bias[f];
#pragma unroll
    for (int k = 0; k < 64; ++k) acc = fmaf(sh[w][k], sWt[k * 65 + f], acc);
    if (n < N) inout[(long)n * F + f] = fmaxf(acc, 0.0f);
}

extern "C" void kernel_launch(void* const* d_in, const int* in_sizes, int n_in,
                              void* d_out, int out_size, void* d_ws, size_t ws_size,
                              hipStream_t stream) {
    const float* feature = (const float*)d_in[0];
    const int*   esrc    = (const int*)d_in[1];
    const int*   edst    = (const int*)d_in[2];
    const float* W       = (const float*)d_in[3];
    const float* bias    = (const float*)d_in[4];

    int N = in_sizes[0] / F;   // 50000
    int E = in_sizes[1];       // 800000

    int NSH  = (N + SHW - 1) / SHW;            // 196
    int CAPS = (E / (NSH > 0 ? NSH : 1)) * 5 / 4 + 64;

    auto align256 = [](size_t x) { return (x + 255) & ~(size_t)255; };
    size_t sz_deg    = align256((size_t)N * sizeof(int));
    size_t sz_ovfA   = align256((2 + 2 * (size_t)OVF_MAX) * sizeof(int));
    size_t sz_ovfB   = align256((2 + 2 * (size_t)OVF_MAX) * sizeof(int));
    size_t sz_cur    = align256(256 * sizeof(int));
    size_t sz_bucket = align256((size_t)N * CAP * sizeof(int));
    size_t sz_Y      = align256((size_t)N * F * sizeof(ushort));
    size_t sz_shard  = align256((size_t)NSH * CAPS * sizeof(int2));
    size_t need_mid  = sz_deg + sz_ovfA + sz_ovfB + sz_cur + sz_bucket + sz_Y;
    size_t need_new  = need_mid + sz_shard;

    int n4 = (N + 3) / 4;

    if (ws_size >= need_mid && NSH <= 256) {
        char* ws = (char*)d_ws;
        int*    deg    = (int*)ws;    ws += sz_deg;
        int*    ovfA   = (int*)ws;    ws += sz_ovfA;
        int*    ovfB   = (int*)ws;    ws += sz_ovfB;
        int*    cursor = (int*)ws;    ws += sz_cur;
        int*    bucket = (int*)ws;    ws += sz_bucket;
        ushort* Ybf    = (ushort*)ws; ws += sz_Y;
        float*  out    = (float*)d_out;

        k_gemm<<<(N + 31) / 32, 256, 0, stream>>>(feature, W, Ybf, N, deg, n4,
                                                  cursor, ovfA, ovfB);
        if (ws_size >= need_new) {
            int2* shardBuf = (int2*)ws;
            int gSh = (E + 2047) / 2048;
            k_shard<<<gSh, 256, 0, stream>>>(esrc, edst, cursor, shardBuf,
                                             ovfA, E, NSH, CAPS);
            k_bin<<<NSH, 256, 0, stream>>>(shardBuf, cursor, ovfA, deg, bucket,
                                           ovfB, N, CAPS);
        } else {
            int gE4 = (E + 1023) / 1024;
            k_scatter13<<<gE4, 256, 0, stream>>>(esrc, edst, deg, bucket, ovfB, E);
        }
        k_gather<<<(N + 3) / 4, 256, 0, stream>>>(Ybf, deg, bucket, ovfB, bias, out, N);
    } else {
        float* agg = (float*)d_out;
        float* cnt = (float*)d_ws;
        hipMemsetAsync(agg, 0, (size_t)N * F * sizeof(float), stream);
        hipMemsetAsync(cnt, 0, (size_t)N * sizeof(float), stream);
        long total = (long)E * F;
        gcn_edge_scatter<<<(int)((total + 255) / 256), 256, 0, stream>>>(
            feature, esrc, edst, agg, cnt, E);
        gcn_node_apply<<<(N + 3) / 4, 256, 0, stream>>>(feature, W, bias, cnt, agg, N);
    }
}

// Round 17
// 63.525 us; speedup vs baseline: 1.6974x; 1.1803x over previous
//
#include <hip/hip_runtime.h>

// GCN layer: out = relu( G(feature) @ W^T + b ), G = mean over in-edges (or
// identity for isolated nodes).  N=50000, F=64, E=800000.
//
// GEMM commutes with the aggregation: G(feat)@W^T == G(feat@W^T).
// Round-17: TWO dispatches.
//  D1 k_work (role split): blocks [0,G) GEMM Ybf=bf16(feat@W^T); blocks
//     [G,G+S) shard-sort 2048 edges each into a private slab (deterministic,
//     atomic-free: LDS histogram by shard=dst>>8, scan, stage, linear dump)
//     + per-block prefix table pfxTab[b][257]. Packed entry: (dst&255)<<24|src.
//  D2 k_bingather (1 block/shard, 1024 thr): bin all runs for this shard into
//     a 48KB LDS bucket (LDS atomics), then gather-mean+bias+relu for its 256
//     nodes reading the bucket from LDS. No global deg/bucket at all.
// ovfB list keeps deg>CAP correctness (empty here; 0xAA poison can't
// false-match a node id, count reset each call by k_work).

#define F 64
#define CAP 48          // bucket slots per node
#define SHW 256         // nodes per shard
#define EB 2048         // edges per shard block
#define OVF_MAX 32768

typedef unsigned int uint;
typedef unsigned short ushort;

__device__ __forceinline__ ushort f2bf(float x) {
    uint u = __float_as_uint(x);
    u += 0x7FFFu + ((u >> 16) & 1u);   // round-to-nearest-even
    return (ushort)(u >> 16);
}

// ---------- D1: role-split GEMM + shard sort ----------
__global__ __launch_bounds__(256) void k_work(const float* __restrict__ feature,
                                              const float* __restrict__ W,
                                              ushort* __restrict__ Ybf,
                                              const int* __restrict__ esrc,
                                              const int* __restrict__ edst,
                                              int* __restrict__ blkBuf,
                                              int* __restrict__ pfxTab,
                                              int* __restrict__ ovfB,
                                              int N, int E, int G) {
    __shared__ alignas(16) char smem[28672];
    int tid = threadIdx.x, bid = blockIdx.x;
    if (bid == 0 && tid == 0) ovfB[0] = 0;

    if (bid < G) {
        // ---- GEMM role: 32 nodes/block ----
        float* sWt = (float*)smem;              // 64*76 floats = 19456B
        float* shh = (float*)(smem + 19456);    // 32*72 floats =  9216B
        for (int i = tid; i < 4096; i += 256) {
            int fo = i >> 6, k = i & 63;
            sWt[k * 76 + fo] = W[i];
        }
        int n0blk = bid * 32;
        for (int i = tid; i < 512; i += 256) {  // 32 rows x 16 float4
            int r = i >> 4, c4 = i & 15;
            int n = n0blk + r;
            float4 v = make_float4(0.f, 0.f, 0.f, 0.f);
            if (n < N) v = ((const float4*)feature)[(long)n * 16 + c4];
            *(float4*)&shh[r * 72 + c4 * 4] = v;
        }
        __syncthreads();
        int npair = tid >> 4, foq = tid & 15;
        int r0 = npair * 2, r1 = r0 + 1;
        float a0=0,a1=0,a2=0,a3=0,b0=0,b1=0,b2=0,b3=0;
#pragma unroll 8
        for (int k = 0; k < 64; ++k) {
            float hA = shh[r0 * 72 + k];
            float hB = shh[r1 * 72 + k];
            float4 wv = *(const float4*)&sWt[k * 76 + foq * 4];
            a0 = fmaf(hA, wv.x, a0); a1 = fmaf(hA, wv.y, a1);
            a2 = fmaf(hA, wv.z, a2); a3 = fmaf(hA, wv.w, a3);
            b0 = fmaf(hB, wv.x, b0); b1 = fmaf(hB, wv.y, b1);
            b2 = fmaf(hB, wv.z, b2); b3 = fmaf(hB, wv.w, b3);
        }
        int nA = n0blk + r0, nB = n0blk + r1;
        if (nA < N) ((ushort4*)Ybf)[(long)nA * 16 + foq] =
            make_ushort4(f2bf(a0), f2bf(a1), f2bf(a2), f2bf(a3));
        if (nB < N) ((ushort4*)Ybf)[(long)nB * 16 + foq] =
            make_ushort4(f2bf(b0), f2bf(b1), f2bf(b2), f2bf(b3));
    } else {
        // ---- shard role: sort 2048 edges by shard, dump slab + pfx ----
        int* cnt   = (int*)smem;                // 256
        int* sc    = (int*)(smem + 1024);       // 256
        int* pfx   = (int*)(smem + 2048);       // 256
        int* off   = (int*)(smem + 3072);       // 256
        int* stage = (int*)(smem + 4096);       // 2048 ints

        int b = bid - G;
        int ebase = b * EB;
        int d[8], s[8];
        int i0 = ebase + tid * 8;
        if (i0 + 7 < E) {
            int4 a  = *(const int4*)(edst + i0);
            int4 b4 = *(const int4*)(edst + i0 + 4);
            d[0]=a.x; d[1]=a.y; d[2]=a.z; d[3]=a.w;
            d[4]=b4.x; d[5]=b4.y; d[6]=b4.z; d[7]=b4.w;
            int4 c4 = *(const int4*)(esrc + i0);
            int4 e4 = *(const int4*)(esrc + i0 + 4);
            s[0]=c4.x; s[1]=c4.y; s[2]=c4.z; s[3]=c4.w;
            s[4]=e4.x; s[5]=e4.y; s[6]=e4.z; s[7]=e4.w;
        } else {
#pragma unroll
            for (int k = 0; k < 8; ++k) {
                int e = i0 + k;
                d[k] = (e < E) ? edst[e] : -1;
                s[k] = (e < E) ? esrc[e] : 0;
            }
        }
        cnt[tid] = 0;
        __syncthreads();
#pragma unroll
        for (int k = 0; k < 8; ++k)
            if (d[k] >= 0) atomicAdd(&cnt[d[k] >> 8], 1);
        __syncthreads();
        int own = cnt[tid];
        sc[tid] = own;
        __syncthreads();
        for (int dd = 1; dd < 256; dd <<= 1) {
            int t = (tid >= dd) ? sc[tid - dd] : 0;
            __syncthreads();
            sc[tid] += t;
            __syncthreads();
        }
        pfx[tid] = sc[tid] - own;
        off[tid] = sc[tid] - own;
        __syncthreads();
#pragma unroll
        for (int k = 0; k < 8; ++k) {
            if (d[k] >= 0) {
                int sh = d[k] >> 8;
                int sl = atomicAdd(&off[sh], 1);
                stage[sl] = ((d[k] & 255) << 24) | s[k];   // N < 2^24 guard in host
            }
        }
        __syncthreads();
        int total = pfx[255] + cnt[255];
        for (int i = tid; i < total; i += 256)
            blkBuf[ebase + i] = stage[i];                   // coalesced dump
        pfxTab[b * 257 + tid] = pfx[tid];
        if (tid == 0) pfxTab[b * 257 + 256] = total;
    }
}

// ---------- D2: per-shard bin (LDS) + gather-mean + bias + relu ----------
__global__ __launch_bounds__(1024) void k_bingather(const ushort* __restrict__ Ybf,
                                                    const int* __restrict__ blkBuf,
                                                    const int* __restrict__ pfxTab,
                                                    int* __restrict__ ovfB,
                                                    const float* __restrict__ bias,
                                                    float* __restrict__ out,
                                                    int N, int S) {
    __shared__ int dl[SHW];
    __shared__ int bl[SHW * CAP];   // 48KB
    int tid = threadIdx.x;
    int sh  = blockIdx.x;
    for (int i = tid; i < SHW; i += 1024) dl[i] = 0;
    __syncthreads();
    // bin: one thread per source block's run
    for (int b = tid; b < S; b += 1024) {
        int lo = pfxTab[b * 257 + sh];
        int hi = pfxTab[b * 257 + sh + 1];
        for (int i = lo; i < hi; ++i) {
            int v = blkBuf[b * EB + i];
            int lid = ((uint)v) >> 24;
            int s = v & 0xFFFFFF;
            int r = atomicAdd(&dl[lid], 1);
            if (r < CAP) bl[lid * CAP + r] = s;
            else { int o = atomicAdd(&ovfB[0], 1);
                   if (o < OVF_MAX) { ovfB[2 + 2*o] = sh * SHW + lid; ovfB[3 + 2*o] = s; } }
        }
    }
    __syncthreads();
    // gather: 16 waves x 16 passes = 256 nodes
    int wv = tid >> 6, lane = tid & 63;
    int g = lane >> 3, c = lane & 7;
    const uint4* Y16 = (const uint4*)Ybf;
    for (int pass = 0; pass < SHW / 16; ++pass) {
        int lid = pass * 16 + wv;
        int n = sh * SHW + lid;
        if (n < N) {
            int d = dl[lid];
            int m = min(d, CAP);
            float acc[4][8];
#pragma unroll
            for (int ch = 0; ch < 4; ++ch)
#pragma unroll
                for (int j = 0; j < 8; ++j) acc[ch][j] = 0.f;
            int last = m - 1;
            for (int base = 0; base < m; base += 32) {
#pragma unroll
                for (int ch = 0; ch < 4; ++ch) {
                    int jdx = base + ch * 8 + g;
                    int s = bl[lid * CAP + min(jdx, last)];
                    uint4 q = Y16[(long)s * 8 + c];
                    if (jdx < m) {
                        acc[ch][0] += __uint_as_float(q.x << 16);
                        acc[ch][1] += __uint_as_float(q.x & 0xFFFF0000u);
                        acc[ch][2] += __uint_as_float(q.y << 16);
                        acc[ch][3] += __uint_as_float(q.y & 0xFFFF0000u);
                        acc[ch][4] += __uint_as_float(q.z << 16);
                        acc[ch][5] += __uint_as_float(q.z & 0xFFFF0000u);
                        acc[ch][6] += __uint_as_float(q.w << 16);
                        acc[ch][7] += __uint_as_float(q.w & 0xFFFF0000u);
                    }
                }
            }
            if (d > CAP) {   // overflow tail (empty for this input)
                int no = ovfB[0]; if (no > OVF_MAX) no = OVF_MAX;
                if (g == 0) {
                    for (int i = 0; i < no; ++i) {
                        if (ovfB[2 + 2*i] == n) {
                            int s = ovfB[3 + 2*i];
                            uint4 q = Y16[(long)s * 8 + c];
                            acc[0][0] += __uint_as_float(q.x << 16);
                            acc[0][1] += __uint_as_float(q.x & 0xFFFF0000u);
                            acc[0][2] += __uint_as_float(q.y << 16);
                            acc[0][3] += __uint_as_float(q.y & 0xFFFF0000u);
                            acc[0][4] += __uint_as_float(q.z << 16);
                            acc[0][5] += __uint_as_float(q.z & 0xFFFF0000u);
                            acc[0][6] += __uint_as_float(q.w << 16);
                            acc[0][7] += __uint_as_float(q.w & 0xFFFF0000u);
                        }
                    }
                }
            }
#pragma unroll
            for (int j = 0; j < 8; ++j)
                acc[0][j] += (acc[1][j] + acc[2][j]) + acc[3][j];
#pragma unroll
            for (int j = 0; j < 8; ++j) {
                float v = acc[0][j];
                v += __shfl_xor(v, 8);
                v += __shfl_xor(v, 16);
                v += __shfl_xor(v, 32);
                acc[0][j] = v;
            }
            float sel = acc[0][0];
#pragma unroll
            for (int j = 1; j < 8; ++j) sel = (g == j) ? acc[0][j] : sel;
            int fw = c * 8 + g;
            float hv;
            if (d > 0) hv = sel / (float)d;
            else       hv = __uint_as_float(((uint)Ybf[(long)n * F + fw]) << 16);
            out[(long)n * F + fw] = fmaxf(hv + bias[fw], 0.0f);
        }
    }
}

// ================= mid-tier (R13/R16 proven): gemm+zero -> atomic scatter ->
// global-bucket gather ==========================================
__global__ __launch_bounds__(256) void k_gemm13(const float* __restrict__ feature,
                                                const float* __restrict__ W,
                                                ushort* __restrict__ Ybf, int N,
                                                int* __restrict__ deg, int n4,
                                                int* __restrict__ ovfB) {
    {
        int gt = blockIdx.x * 256 + threadIdx.x;
        if (gt == 0) ovfB[0] = 0;
        for (int i = gt; i < n4; i += gridDim.x * 256)
            ((int4*)deg)[i] = make_int4(0, 0, 0, 0);
    }
    __shared__ float sWt[64 * 76];
    __shared__ float shh[32 * 72];
    int tid = threadIdx.x;
    for (int i = tid; i < 4096; i += 256) {
        int fo = i >> 6, k = i & 63;
        sWt[k * 76 + fo] = W[i];
    }
    int n0blk = blockIdx.x * 32;
    for (int i = tid; i < 512; i += 256) {
        int r = i >> 4, c4 = i & 15;
        int n = n0blk + r;
        float4 v = make_float4(0.f, 0.f, 0.f, 0.f);
        if (n < N) v = ((const float4*)feature)[(long)n * 16 + c4];
        *(float4*)&shh[r * 72 + c4 * 4] = v;
    }
    __syncthreads();
    int npair = tid >> 4, foq = tid & 15;
    int r0 = npair * 2, r1 = r0 + 1;
    float a0=0,a1=0,a2=0,a3=0,b0=0,b1=0,b2=0,b3=0;
#pragma unroll 8
    for (int k = 0; k < 64; ++k) {
        float hA = shh[r0 * 72 + k];
        float hB = shh[r1 * 72 + k];
        float4 wv = *(const float4*)&sWt[k * 76 + foq * 4];
        a0 = fmaf(hA, wv.x, a0); a1 = fmaf(hA, wv.y, a1);
        a2 = fmaf(hA, wv.z, a2); a3 = fmaf(hA, wv.w, a3);
        b0 = fmaf(hB, wv.x, b0); b1 = fmaf(hB, wv.y, b1);
        b2 = fmaf(hB, wv.z, b2); b3 = fmaf(hB, wv.w, b3);
    }
    int nA = n0blk + r0, nB = n0blk + r1;
    if (nA < N) ((ushort4*)Ybf)[(long)nA * 16 + foq] =
        make_ushort4(f2bf(a0), f2bf(a1), f2bf(a2), f2bf(a3));
    if (nB < N) ((ushort4*)Ybf)[(long)nB * 16 + foq] =
        make_ushort4(f2bf(b0), f2bf(b1), f2bf(b2), f2bf(b3));
}

__global__ __launch_bounds__(256) void k_scatter13(const int* __restrict__ esrc,
                                                   const int* __restrict__ edst,
                                                   int* __restrict__ deg,
                                                   int* __restrict__ bucket,
                                                   int* __restrict__ ovfB, int E) {
    int base = (blockIdx.x * 256 + threadIdx.x) * 4;
    if (base + 3 < E) {
        int4 d4 = *(const int4*)(edst + base);
        int4 s4 = *(const int4*)(esrc + base);
        int r0 = atomicAdd(&deg[d4.x], 1);
        int r1 = atomicAdd(&deg[d4.y], 1);
        int r2 = atomicAdd(&deg[d4.z], 1);
        int r3 = atomicAdd(&deg[d4.w], 1);
        if (r0 < CAP) bucket[d4.x * CAP + r0] = s4.x;
        else { int o = atomicAdd(&ovfB[0], 1); if (o < OVF_MAX) { ovfB[2 + 2*o] = d4.x; ovfB[3 + 2*o] = s4.x; } }
        if (r1 < CAP) bucket[d4.y * CAP + r1] = s4.y;
        else { int o = atomicAdd(&ovfB[0], 1); if (o < OVF_MAX) { ovfB[2 + 2*o] = d4.y; ovfB[3 + 2*o] = s4.y; } }
        if (r2 < CAP) bucket[d4.z * CAP + r2] = s4.z;
        else { int o = atomicAdd(&ovfB[0], 1); if (o < OVF_MAX) { ovfB[2 + 2*o] = d4.z; ovfB[3 + 2*o] = s4.z; } }
        if (r3 < CAP) bucket[d4.w * CAP + r3] = s4.w;
        else { int o = atomicAdd(&ovfB[0], 1); if (o < OVF_MAX) { ovfB[2 + 2*o] = d4.w; ovfB[3 + 2*o] = s4.w; } }
    } else {
        for (int e = base; e < E; ++e) {
            int d = edst[e], s = esrc[e];
            int r = atomicAdd(&deg[d], 1);
            if (r < CAP) bucket[d * CAP + r] = s;
            else { int o = atomicAdd(&ovfB[0], 1); if (o < OVF_MAX) { ovfB[2 + 2*o] = d; ovfB[3 + 2*o] = s; } }
        }
    }
}

__global__ __launch_bounds__(256) void k_gatherG(const ushort* __restrict__ Ybf,
                                                 const int* __restrict__ deg,
                                                 const int* __restrict__ bucket,
                                                 const int* __restrict__ ovf,
                                                 const float* __restrict__ bias,
                                                 float* __restrict__ out, int N) {
    int tid = threadIdx.x;
    int w = tid >> 6, lane = tid & 63;
    int g = lane >> 3, c = lane & 7;
    int n = blockIdx.x * 4 + w;
    if (n >= N) return;
    int d = deg[n];
    int m = min(d, CAP);
    int boff = n * CAP;
    const uint4* Y16 = (const uint4*)Ybf;
    float acc[4][8];
#pragma unroll
    for (int ch = 0; ch < 4; ++ch)
#pragma unroll
        for (int j = 0; j < 8; ++j) acc[ch][j] = 0.f;
    int last = m - 1;
    for (int base = 0; base < m; base += 32) {
#pragma unroll
        for (int ch = 0; ch < 4; ++ch) {
            int jdx = base + ch * 8 + g;
            int s = bucket[boff + min(jdx, last)];
            uint4 q = Y16[(long)s * 8 + c];
            if (jdx < m) {
                acc[ch][0] += __uint_as_float(q.x << 16);
                acc[ch][1] += __uint_as_float(q.x & 0xFFFF0000u);
                acc[ch][2] += __uint_as_float(q.y << 16);
                acc[ch][3] += __uint_as_float(q.y & 0xFFFF0000u);
                acc[ch][4] += __uint_as_float(q.z << 16);
                acc[ch][5] += __uint_as_float(q.z & 0xFFFF0000u);
                acc[ch][6] += __uint_as_float(q.w << 16);
                acc[ch][7] += __uint_as_float(q.w & 0xFFFF0000u);
            }
        }
    }
    if (d > CAP) {
        int no = ovf[0]; if (no > OVF_MAX) no = OVF_MAX;
        if (g == 0) {
            for (int i = 0; i < no; ++i) {
                if (ovf[2 + 2*i] == n) {
                    int s = ovf[3 + 2*i];
                    uint4 q = Y16[(long)s * 8 + c];
                    acc[0][0] += __uint_as_float(q.x << 16);
                    acc[0][1] += __uint_as_float(q.x & 0xFFFF0000u);
                    acc[0][2] += __uint_as_float(q.y << 16);
                    acc[0][3] += __uint_as_float(q.y & 0xFFFF0000u);
                    acc[0][4] += __uint_as_float(q.z << 16);
                    acc[0][5] += __uint_as_float(q.z & 0xFFFF0000u);
                    acc[0][6] += __uint_as_float(q.w << 16);
                    acc[0][7] += __uint_as_float(q.w & 0xFFFF0000u);
                }
            }
        }
    }
#pragma unroll
    for (int j = 0; j < 8; ++j)
        acc[0][j] += (acc[1][j] + acc[2][j]) + acc[3][j];
#pragma unroll
    for (int j = 0; j < 8; ++j) {
        float v = acc[0][j];
        v += __shfl_xor(v, 8);
        v += __shfl_xor(v, 16);
        v += __shfl_xor(v, 32);
        acc[0][j] = v;
    }
    float sel = acc[0][0];
#pragma unroll
    for (int j = 1; j < 8; ++j) sel = (g == j) ? acc[0][j] : sel;
    int fw = c * 8 + g;
    float hv;
    if (d > 0) hv = sel / (float)d;
    else       hv = __uint_as_float(((uint)Ybf[(long)n * F + fw]) << 16);
    out[(long)n * F + fw] = fmaxf(hv + bias[fw], 0.0f);
}

// ---------- tier C: pure atomic (tiny ws) ----------
__global__ __launch_bounds__(256) void gcn_edge_scatter(const float* __restrict__ feature,
                                                        const int* __restrict__ esrc,
                                                        const int* __restrict__ edst,
                                                        float* __restrict__ agg,
                                                        float* __restrict__ cnt, int E) {
    int t = blockIdx.x * blockDim.x + threadIdx.x;
    int e = t >> 6, f = t & 63;
    if (e >= E) return;
    atomicAdd(&agg[(long)edst[e] * F + f], feature[(long)esrc[e] * F + f]);
    if (f == 0) atomicAdd(&cnt[edst[e]], 1.0f);
}
__global__ __launch_bounds__(256) void gcn_node_apply(const float* __restrict__ feature,
                                                      const float* __restrict__ W,
                                                      const float* __restrict__ bias,
                                                      const float* __restrict__ cnt,
                                                      float* __restrict__ inout, int N) {
    __shared__ float sWt[64 * 65];
    __shared__ float sh[4][64];
    int tid = threadIdx.x;
    for (int i = tid; i < 64 * 64; i += 256) {
        int fo = i >> 6, k = i & 63;
        sWt[k * 65 + fo] = W[i];
    }
    int w = tid >> 6, f = tid & 63;
    int n = blockIdx.x * 4 + w;
    float h = 0.0f;
    if (n < N) {
        float c = cnt[n];
        h = (c > 0.0f) ? inout[(long)n * F + f] / c : feature[(long)n * F + f];
    }
    sh[w][f] = h;
    __syncthreads();
    float acc = bias[f];
#pragma unroll
    for (int k = 0; k < 64; ++k) acc = fmaf(sh[w][k], sWt[k * 65 + f], acc);
    if (n < N) inout[(long)n * F + f] = fmaxf(acc, 0.0f);
}

extern "C" void kernel_launch(void* const* d_in, const int* in_sizes, int n_in,
                              void* d_out, int out_size, void* d_ws, size_t ws_size,
                              hipStream_t stream) {
    const float* feature = (const float*)d_in[0];
    const int*   esrc    = (const int*)d_in[1];
    const int*   edst    = (const int*)d_in[2];
    const float* W       = (const float*)d_in[3];
    const float* bias    = (const float*)d_in[4];

    int N = in_sizes[0] / F;   // 50000
    int E = in_sizes[1];       // 800000

    int G   = (N + 31) / 32;           // GEMM blocks
    int S   = (E + EB - 1) / EB;       // shard blocks
    int NSH = (N + SHW - 1) / SHW;     // shards

    auto align256 = [](size_t x) { return (x + 255) & ~(size_t)255; };
    size_t sz_ovf = align256((2 + 2 * (size_t)OVF_MAX) * sizeof(int));
    size_t sz_Y   = align256((size_t)N * F * sizeof(ushort));
    size_t sz_blk = align256((size_t)S * EB * sizeof(int));
    size_t sz_pfx = align256((size_t)S * 257 * sizeof(int));
    size_t need_new = sz_ovf + sz_Y + sz_blk + sz_pfx;

    size_t sz_deg    = align256((size_t)N * sizeof(int));
    size_t sz_bucket = align256((size_t)N * CAP * sizeof(int));
    size_t need_mid  = sz_ovf + sz_Y + sz_deg + sz_bucket;

    if (ws_size >= need_new && N <= 65536) {   // 256-bin histogram + 24-bit src pack
        char* ws = (char*)d_ws;
        int*    ovfB   = (int*)ws;    ws += sz_ovf;
        ushort* Ybf    = (ushort*)ws; ws += sz_Y;
        int*    blkBuf = (int*)ws;    ws += sz_blk;
        int*    pfxTab = (int*)ws;
        float*  out    = (float*)d_out;

        k_work<<<G + S, 256, 0, stream>>>(feature, W, Ybf, esrc, edst,
                                          blkBuf, pfxTab, ovfB, N, E, G);
        k_bingather<<<NSH, 1024, 0, stream>>>(Ybf, blkBuf, pfxTab, ovfB,
                                              bias, out, N, S);
    } else if (ws_size >= need_mid) {
        char* ws = (char*)d_ws;
        int*    ovfB   = (int*)ws;    ws += sz_ovf;
        ushort* Ybf    = (ushort*)ws; ws += sz_Y;
        int*    deg    = (int*)ws;    ws += sz_deg;
        int*    bucket = (int*)ws;
        float*  out    = (float*)d_out;
        int n4 = (N + 3) / 4;
        int gE4 = (E + 1023) / 1024;

        k_gemm13<<<G, 256, 0, stream>>>(feature, W, Ybf, N, deg, n4, ovfB);
        k_scatter13<<<gE4, 256, 0, stream>>>(esrc, edst, deg, bucket, ovfB, E);
        k_gatherG<<<(N + 3) / 4, 256, 0, stream>>>(Ybf, deg, bucket, ovfB, bias, out, N);
    } else {
        float* agg = (float*)d_out;
        float* cnt = (float*)d_ws;
        hipMemsetAsync(agg, 0, (size_t)N * F * sizeof(float), stream);
        hipMemsetAsync(cnt, 0, (size_t)N * sizeof(float), stream);
        long total = (long)E * F;
        gcn_edge_scatter<<<(int)((total + 255) / 256), 256, 0, stream>>>(
            feature, esrc, edst, agg, cnt, E);
        gcn_node_apply<<<(N + 3) / 4, 256, 0, stream>>>(feature, W, bias, cnt, agg, N);
    }
}